// Round 2
// baseline (570.510 us; speedup 1.0000x reference)
//
#include <hip/hip_runtime.h>
#include <hip/hip_bf16.h>

// ProcessContinuous: out[b,m, d*4+k] with k = {0:pot, 1:call, 2:stack, 3:odds}
//   emb_X[d] = relu(scalar_X * X_w[d] + X_b[d])
//   scalars: hero_stack = x[...,0], amnt_to_call = x[...,5], pot_odds = x[...,6]
//
// Pure store-BW kernel: 537 MB out vs 17 MB in. Roofline ~88 us at 6.3 TB/s.
// R2: unroll x4 (12 loads in flight before first use) + non-temporal stores
// (output has zero reuse; keep it out of L2).

#define C_DIM 16
#define D_DIM 128

typedef float f32x4 __attribute__((ext_vector_type(4)));

__global__ __launch_bounds__(256) void ProcessContinuous_30786325577969_kernel(
    const float* __restrict__ x,
    const float* __restrict__ stack_w, const float* __restrict__ stack_b,
    const float* __restrict__ call_w,  const float* __restrict__ call_b,
    const float* __restrict__ odds_w,  const float* __restrict__ odds_b,
    const float* __restrict__ pot_w,   const float* __restrict__ pot_b,
    f32x4* __restrict__ out, int nrows)
{
    const int d = threadIdx.x & (D_DIM - 1);

    // Per-thread weights live in registers for the whole grid-stride loop.
    const float sw = stack_w[d], sb = stack_b[d];
    const float cw = call_w[d],  cb = call_b[d];
    const float ow = odds_w[d],  ob = odds_b[d];
    const float pw = pot_w[d],   pb = pot_b[d];

    const int S = gridDim.x * 2;                 // rows advanced per unroll slot
    int row = blockIdx.x * 2 + (threadIdx.x >> 7);

    // Main loop: 4 rows in flight -> 12 independent loads issued before use.
    for (; row + 3 * S < nrows; row += 4 * S) {
        const float* x0 = x + (size_t)row * C_DIM;
        const float* x1 = x + (size_t)(row + S) * C_DIM;
        const float* x2 = x + (size_t)(row + 2 * S) * C_DIM;
        const float* x3 = x + (size_t)(row + 3 * S) * C_DIM;

        const float hs0 = x0[0], ac0 = x0[5], po0 = x0[6];
        const float hs1 = x1[0], ac1 = x1[5], po1 = x1[6];
        const float hs2 = x2[0], ac2 = x2[5], po2 = x2[6];
        const float hs3 = x3[0], ac3 = x3[5], po3 = x3[6];

        f32x4 v0, v1, v2, v3;
        v0.x = fmaxf(fmaf(po0, pw, pb), 0.0f);
        v0.y = fmaxf(fmaf(ac0, cw, cb), 0.0f);
        v0.z = fmaxf(fmaf(hs0, sw, sb), 0.0f);
        v0.w = fmaxf(fmaf(po0, ow, ob), 0.0f);

        v1.x = fmaxf(fmaf(po1, pw, pb), 0.0f);
        v1.y = fmaxf(fmaf(ac1, cw, cb), 0.0f);
        v1.z = fmaxf(fmaf(hs1, sw, sb), 0.0f);
        v1.w = fmaxf(fmaf(po1, ow, ob), 0.0f);

        v2.x = fmaxf(fmaf(po2, pw, pb), 0.0f);
        v2.y = fmaxf(fmaf(ac2, cw, cb), 0.0f);
        v2.z = fmaxf(fmaf(hs2, sw, sb), 0.0f);
        v2.w = fmaxf(fmaf(po2, ow, ob), 0.0f);

        v3.x = fmaxf(fmaf(po3, pw, pb), 0.0f);
        v3.y = fmaxf(fmaf(ac3, cw, cb), 0.0f);
        v3.z = fmaxf(fmaf(hs3, sw, sb), 0.0f);
        v3.w = fmaxf(fmaf(po3, ow, ob), 0.0f);

        __builtin_nontemporal_store(v0, &out[(size_t)row * D_DIM + d]);
        __builtin_nontemporal_store(v1, &out[(size_t)(row + S) * D_DIM + d]);
        __builtin_nontemporal_store(v2, &out[(size_t)(row + 2 * S) * D_DIM + d]);
        __builtin_nontemporal_store(v3, &out[(size_t)(row + 3 * S) * D_DIM + d]);
    }

    // Tail (not taken for nrows=262144, grid=2048, but keep it general).
    for (; row < nrows; row += S) {
        const float* xr = x + (size_t)row * C_DIM;
        const float hs = xr[0], ac = xr[5], po = xr[6];
        f32x4 v;
        v.x = fmaxf(fmaf(po, pw, pb), 0.0f);
        v.y = fmaxf(fmaf(ac, cw, cb), 0.0f);
        v.z = fmaxf(fmaf(hs, sw, sb), 0.0f);
        v.w = fmaxf(fmaf(po, ow, ob), 0.0f);
        __builtin_nontemporal_store(v, &out[(size_t)row * D_DIM + d]);
    }
}

extern "C" void kernel_launch(void* const* d_in, const int* in_sizes, int n_in,
                              void* d_out, int out_size, void* d_ws, size_t ws_size,
                              hipStream_t stream) {
    const float* x       = (const float*)d_in[0];
    const float* stack_w = (const float*)d_in[1];
    const float* stack_b = (const float*)d_in[2];
    const float* call_w  = (const float*)d_in[3];
    const float* call_b  = (const float*)d_in[4];
    const float* odds_w  = (const float*)d_in[5];
    const float* odds_b  = (const float*)d_in[6];
    const float* pot_w   = (const float*)d_in[7];
    const float* pot_b   = (const float*)d_in[8];

    const int nrows = in_sizes[0] / C_DIM;   // B*M = 262144

    const int block = 256;                   // 2 rows per block-iteration
    int grid = 2048;                         // 8 blocks/CU -> full occupancy
    const int rowPairs = (nrows + 1) / 2;
    if (grid > rowPairs) grid = rowPairs;

    ProcessContinuous_30786325577969_kernel<<<grid, block, 0, stream>>>(
        x, stack_w, stack_b, call_w, call_b, odds_w, odds_b, pot_w, pot_b,
        (f32x4*)d_out, nrows);
}

// Round 3
// 552.557 us; speedup vs baseline: 1.0325x; 1.0325x over previous
//
#include <hip/hip_runtime.h>
#include <hip/hip_bf16.h>

// ProcessContinuous: out[b,m, d*4+k] with k = {0:pot, 1:call, 2:stack, 3:odds}
//   emb_X[d] = relu(scalar_X * X_w[d] + X_b[d])
//   scalars: hero_stack = x[...,0], amnt_to_call = x[...,5], pot_odds = x[...,6]
//
// Pure store-BW kernel: 537 MB out + 17 MB in -> ~88 us floor at 6.3 TB/s.
// R3: revert R2's unroll+nontemporal (19 us regression / noise); R1 structure
// was the best measured. One 128-thread group per row, weights in registers,
// one coalesced float4 store per lane per row. Full occupancy (2048 blocks
// x 256 thr = 8 blocks/CU = 32 waves/CU) hides the uniform-load latency.

#define C_DIM 16
#define D_DIM 128

__global__ __launch_bounds__(256) void ProcessContinuous_30786325577969_kernel(
    const float* __restrict__ x,
    const float* __restrict__ stack_w, const float* __restrict__ stack_b,
    const float* __restrict__ call_w,  const float* __restrict__ call_b,
    const float* __restrict__ odds_w,  const float* __restrict__ odds_b,
    const float* __restrict__ pot_w,   const float* __restrict__ pot_b,
    float4* __restrict__ out, int nrows)
{
    const int d = threadIdx.x & (D_DIM - 1);

    // Per-thread weights live in registers for the whole grid-stride loop.
    const float sw = stack_w[d], sb = stack_b[d];
    const float cw = call_w[d],  cb = call_b[d];
    const float ow = odds_w[d],  ob = odds_b[d];
    const float pw = pot_w[d],   pb = pot_b[d];

    const int rowsPerBlock = blockDim.x >> 7;                 // 2 for 256 threads
    int row    = blockIdx.x * rowsPerBlock + (threadIdx.x >> 7);
    const int stride = gridDim.x * rowsPerBlock;

    for (; row < nrows; row += stride) {
        const float* xr = x + (size_t)row * C_DIM;
        const float hero_stack   = xr[0];   // uniform across the 128-thread group
        const float amnt_to_call = xr[5];
        const float pot_odds     = xr[6];

        float4 v;
        v.x = fmaxf(fmaf(pot_odds,     pw, pb), 0.0f);  // emb_pot
        v.y = fmaxf(fmaf(amnt_to_call, cw, cb), 0.0f);  // emb_call
        v.z = fmaxf(fmaf(hero_stack,   sw, sb), 0.0f);  // emb_stack
        v.w = fmaxf(fmaf(pot_odds,     ow, ob), 0.0f);  // emb_odds

        out[(size_t)row * D_DIM + d] = v;               // coalesced 16 B/lane
    }
}

extern "C" void kernel_launch(void* const* d_in, const int* in_sizes, int n_in,
                              void* d_out, int out_size, void* d_ws, size_t ws_size,
                              hipStream_t stream) {
    const float* x       = (const float*)d_in[0];
    const float* stack_w = (const float*)d_in[1];
    const float* stack_b = (const float*)d_in[2];
    const float* call_w  = (const float*)d_in[3];
    const float* call_b  = (const float*)d_in[4];
    const float* odds_w  = (const float*)d_in[5];
    const float* odds_b  = (const float*)d_in[6];
    const float* pot_w   = (const float*)d_in[7];
    const float* pot_b   = (const float*)d_in[8];

    const int nrows = in_sizes[0] / C_DIM;   // B*M = 262144

    const int block = 256;                   // 2 rows per block-iteration
    int grid = 2048;                         // 8 blocks/CU -> 32 waves/CU (max)
    const int rowPairs = (nrows + 1) / 2;
    if (grid > rowPairs) grid = rowPairs;

    ProcessContinuous_30786325577969_kernel<<<grid, block, 0, stream>>>(
        x, stack_w, stack_b, call_w, call_b, odds_w, odds_b, pot_w, pot_b,
        (float4*)d_out, nrows);
}